// Round 3
// baseline (212.956 us; speedup 1.0000x reference)
//
#include <hip/hip_runtime.h>
#include <hip/hip_bf16.h>

#define NB 2
#define TT 3136
#define DIM 768
#define NH 12
#define NF 16
#define NP 196

typedef __attribute__((ext_vector_type(8))) short short8;
typedef __attribute__((ext_vector_type(4))) short s16x4;
typedef __attribute__((ext_vector_type(4))) float f32x4;
typedef unsigned int uint;

__device__ __forceinline__ float bf2f(short s) {
    return __uint_as_float(((uint)(unsigned short)s) << 16);
}
__device__ __forceinline__ short f2bs(float f) {
    __hip_bfloat16 h = __float2bfloat16(f);
    short s; __builtin_memcpy(&s, &h, 2); return s;
}
__device__ __forceinline__ uint pack2bf(float a, float b) {
    return (uint)(unsigned short)f2bs(a) | ((uint)(unsigned short)f2bs(b) << 16);
}
__device__ __forceinline__ void load16_lds(const void* g, void* l) {
    __builtin_amdgcn_global_load_lds(
        (const __attribute__((address_space(1))) unsigned int*)g,
        (__attribute__((address_space(3))) unsigned int*)l, 16, 0, 0);
}

// -------- prep_all: Wq|Wkv|Wo transpose+bf16, ctx->bf16, LayerNorm(x) ------
// One launch. Blocks [0,2304): weight transpose; [2304,7008): ctx convert;
// [7008,8576): LN, 4 rows/block (one per wave, barrier-free f32x4 + butterfly).
__global__ __launch_bounds__(256)
void prep_all(const float* __restrict__ Wq, const float* __restrict__ Wkv,
              const float* __restrict__ Wo,
              __hip_bfloat16* __restrict__ WqT, __hip_bfloat16* __restrict__ WkvT,
              __hip_bfloat16* __restrict__ WoT,
              const float* __restrict__ ctx, __hip_bfloat16* __restrict__ cb,
              const float* __restrict__ x, const float* __restrict__ gamma,
              const float* __restrict__ beta, __hip_bfloat16* __restrict__ xn) {
    __shared__ float tile[32][33];
    int blk = blockIdx.x, tid = threadIdx.x;
    if (blk < 2304) {
        int bx = blk % 96, ky = blk / 96;
        const float* W; __hip_bfloat16* WT; int N, n0;
        if (bx < 24)      { W = Wq;  WT = WqT;  N = DIM;     n0 = bx * 32; }
        else if (bx < 72) { W = Wkv; WT = WkvT; N = 2 * DIM; n0 = (bx - 24) * 32; }
        else              { W = Wo;  WT = WoT;  N = DIM;     n0 = (bx - 72) * 32; }
        int k0 = ky * 32;
        int tx = tid & 31, ty = tid >> 5;
#pragma unroll
        for (int i = 0; i < 32; i += 8)
            tile[ty + i][tx] = W[(size_t)(k0 + ty + i) * N + (n0 + tx)];
        __syncthreads();
#pragma unroll
        for (int i = 0; i < 32; i += 8)
            WT[(size_t)(n0 + ty + i) * DIM + (k0 + tx)] = __float2bfloat16(tile[tx][ty + i]);
        return;
    }
    blk -= 2304;
    if (blk < 4704) {
        size_t i = (size_t)blk * 256 + tid;
        f32x4 f; __builtin_memcpy(&f, ctx + i * 4, 16);
        s16x4 s;
#pragma unroll
        for (int j = 0; j < 4; j++) s[j] = f2bs(f[j]);
        __builtin_memcpy((short*)cb + i * 4, &s, 8);
        return;
    }
    blk -= 4704;
    // LN: one row per wave, f32x4 loads, 64-lane butterfly (no barriers)
    int wave = tid >> 6, lane = tid & 63;
    int row = blk * 4 + wave;
    const float* xr = x + (size_t)row * DIM;
    f32x4 v[3];
    float s = 0.f, ss = 0.f;
#pragma unroll
    for (int i = 0; i < 3; i++) {
        __builtin_memcpy(&v[i], xr + lane * 4 + i * 256, 16);
#pragma unroll
        for (int j = 0; j < 4; j++) { s += v[i][j]; ss += v[i][j] * v[i][j]; }
    }
#pragma unroll
    for (int off = 32; off; off >>= 1) {
        s += __shfl_xor(s, off);
        ss += __shfl_xor(ss, off);
    }
    float mu = s / DIM;
    float rs = rsqrtf(ss / DIM - mu * mu + 1e-5f);
#pragma unroll
    for (int i = 0; i < 3; i++) {
        int c = lane * 4 + i * 256;
        f32x4 g, bt;
        __builtin_memcpy(&g, gamma + c, 16);
        __builtin_memcpy(&bt, beta + c, 16);
        s16x4 o;
#pragma unroll
        for (int j = 0; j < 4; j++) o[j] = f2bs((v[i][j] - mu) * rs * g[j] + bt[j]);
        __builtin_memcpy((short*)xn + (size_t)row * DIM + c, &o, 8);
    }
}

// -------- gemm_qkv: 256x256xBK64 phase-split template (unchanged r2) ------
__global__ __launch_bounds__(512, 1)
void gemm_qkv(const __hip_bfloat16* __restrict__ xn,
              const __hip_bfloat16* __restrict__ cb,
              const __hip_bfloat16* __restrict__ WqT,
              const __hip_bfloat16* __restrict__ WkvT,
              __hip_bfloat16* __restrict__ qbuf,
              __hip_bfloat16* __restrict__ kvbuf) {
    __shared__ short lds[2][2][2][8192];   // [buf][A/B][half][128*64] = 128 KB

    int orig = blockIdx.x;
    int xcd = orig & 7, pos = orig >> 3;
    int wgid = (xcd < 1 ? xcd * 29 : 29 + (xcd - 1) * 28) + pos;
    int mt = wgid / 9, nt = wgid - mt * 9;

    const __hip_bfloat16 *Abase, *Bbase; __hip_bfloat16* Cbase;
    int N, n0;
    if (nt < 3) { Abase = xn; Bbase = WqT;  Cbase = qbuf;  N = DIM;  n0 = nt * 256; }
    else        { Abase = cb; Bbase = WkvT; Cbase = kvbuf; N = 1536; n0 = (nt - 3) * 256; }
    int m0 = mt * 256;

    int tid = threadIdx.x, lane = tid & 63, wave = tid >> 6;
    int r = lane & 15, q = lane >> 4;
    int wm = wave >> 2, wn = wave & 3;
    f32x4 acc[8][4] = {};

    auto stageK = [&](int buf, int kt) {
        int k0 = kt * 64;
#pragma unroll
        for (int h = 0; h < 2; h++)
#pragma unroll
            for (int s = 0; s < 2; s++) {
                int idx = s * 512 + tid;
                int row = idx >> 3, cg = idx & 7;
                int w = (cg << 4) ^ ((row & 7) << 4);
                int grow = m0 + h * 128 + row;
                if (grow > TT * NB - 1) grow = TT * NB - 1;
                load16_lds((const char*)Abase + ((size_t)grow * DIM + k0) * 2 + w,
                           (char*)&lds[buf][0][h][0] + idx * 16);
            }
#pragma unroll
        for (int h = 0; h < 2; h++)
#pragma unroll
            for (int s = 0; s < 2; s++) {
                int idx = s * 512 + tid;
                int row = idx >> 3, cg = idx & 7;
                int w = (cg << 4) ^ ((row & 7) << 4);
                int grow = n0 + h * 128 + row;
                load16_lds((const char*)Bbase + ((size_t)grow * DIM + k0) * 2 + w,
                           (char*)&lds[buf][1][h][0] + idx * 16);
            }
    };

    auto read_frag = [&](const char* base, int frag, int ks) {
        short8 v;
        int row_ = frag * 16 + r;
        int byte_ = row_ * 128 + ((ks * 64 + q * 16) ^ ((r & 7) << 4));
        __builtin_memcpy(&v, base + byte_, 16);
        return v;
    };

    stageK(0, 0);
    asm volatile("s_waitcnt vmcnt(0)" ::: "memory");
    __builtin_amdgcn_s_barrier();

    for (int t = 0; t < 12; ++t) {
        int cur = t & 1;
        const char* Ah = (const char*)&lds[cur][0][wm][0];
        const char* Bh = (const char*)&lds[cur][1][wn >> 1][0];
        int bbase = (wn & 1) * 4;
        short8 breg[4][2];
#pragma unroll
        for (int p = 0; p < 4; p++) {
            short8 areg[2][2];
#pragma unroll
            for (int i = 0; i < 2; i++)
#pragma unroll
                for (int ks = 0; ks < 2; ks++)
                    areg[i][ks] = read_frag(Ah, p * 2 + i, ks);
            if (p == 0) {
#pragma unroll
                for (int n = 0; n < 4; n++)
#pragma unroll
                    for (int ks = 0; ks < 2; ks++)
                        breg[n][ks] = read_frag(Bh, bbase + n, ks);
                if (t < 11) stageK(cur ^ 1, t + 1);
            }
            __builtin_amdgcn_s_barrier();
            __builtin_amdgcn_s_setprio(1);
#pragma unroll
            for (int i = 0; i < 2; i++)
#pragma unroll
                for (int n = 0; n < 4; n++)
#pragma unroll
                    for (int ks = 0; ks < 2; ks++)
                        acc[p * 2 + i][n] = __builtin_amdgcn_mfma_f32_16x16x32_bf16(
                            areg[i][ks], breg[n][ks], acc[p * 2 + i][n], 0, 0, 0);
            __builtin_amdgcn_s_setprio(0);
            if (p == 3)
                asm volatile("s_waitcnt vmcnt(0)" ::: "memory");
            __builtin_amdgcn_s_barrier();
        }
    }

#pragma unroll
    for (int mf = 0; mf < 8; mf++)
#pragma unroll
        for (int n = 0; n < 4; n++)
#pragma unroll
            for (int rr = 0; rr < 4; rr++) {
                int row = m0 + wm * 128 + mf * 16 + q * 4 + rr;
                if (row < TT * NB) {
                    int col = n0 + wn * 64 + n * 16 + r;
                    Cbase[(size_t)row * N + col] = __float2bfloat16(acc[mf][n][rr]);
                }
            }
}

// -------- gemm_o: out(fp32) = qo @ WoT^T + bo (2-phase dbuf, unchanged) ----
__global__ __launch_bounds__(256)
void gemm_o(const __hip_bfloat16* __restrict__ A,
            const __hip_bfloat16* __restrict__ BT,
            const float* __restrict__ bias,
            float* __restrict__ C) {
    __shared__ short sA[2][128 * 64];
    __shared__ short sB[2][128 * 64];
    int orig = blockIdx.x;
    int xcd = orig & 7, pos = orig >> 3;
    int wgid = (xcd < 6 ? xcd * 37 : 222 + (xcd - 6) * 36) + pos;
    int mt = wgid / 6, nt = wgid - mt * 6;
    int m0 = mt * 128, n0 = nt * 128;
    int tid = threadIdx.x, lane = tid & 63, wave = tid >> 6;
    int r = lane & 15, q = lane >> 4;
    int wm = (wave & 1) * 64, wn = (wave >> 1) * 64;
    f32x4 acc[4][4] = {};

    auto stage = [&](int buf, int k0) {
#pragma unroll
        for (int i = 0; i < 4; i++) {
            int c = i * 256 + tid;
            int row = c >> 3, cg = c & 7;
            load16_lds(A + (size_t)(m0 + row) * DIM + k0 + cg * 8, &sA[buf][c * 8]);
        }
#pragma unroll
        for (int i = 0; i < 4; i++) {
            int c = i * 256 + tid;
            int row = c >> 3, cg = c & 7;
            load16_lds(BT + (size_t)(n0 + row) * DIM + k0 + cg * 8, &sB[buf][c * 8]);
        }
    };
    auto compute = [&](int buf) {
#pragma unroll
        for (int ks = 0; ks < 2; ks++) {
            short8 af[4], bfv[4];
#pragma unroll
            for (int t = 0; t < 4; t++) {
                __builtin_memcpy(&af[t],  &sA[buf][(wm + t * 16 + r) * 64 + ks * 32 + q * 8], 16);
                __builtin_memcpy(&bfv[t], &sB[buf][(wn + t * 16 + r) * 64 + ks * 32 + q * 8], 16);
            }
            __builtin_amdgcn_s_setprio(1);
#pragma unroll
            for (int mi = 0; mi < 4; mi++)
#pragma unroll
                for (int ni = 0; ni < 4; ni++)
                    acc[mi][ni] = __builtin_amdgcn_mfma_f32_16x16x32_bf16(
                        af[mi], bfv[ni], acc[mi][ni], 0, 0, 0);
            __builtin_amdgcn_s_setprio(0);
        }
    };

    stage(0, 0);
    __syncthreads();
    int cur = 0;
#pragma unroll 2
    for (int t = 0; t < 11; ++t) {
        stage(cur ^ 1, (t + 1) * 64);
        compute(cur);
        __syncthreads();
        cur ^= 1;
    }
    compute(cur);

    float bv[4];
#pragma unroll
    for (int ni = 0; ni < 4; ni++) bv[ni] = bias[n0 + wn + ni * 16 + r];
#pragma unroll
    for (int mi = 0; mi < 4; mi++)
#pragma unroll
        for (int ni = 0; ni < 4; ni++)
#pragma unroll
            for (int rr = 0; rr < 4; rr++) {
                int row = m0 + wm + mi * 16 + q * 4 + rr;
                int col = n0 + wn + ni * 16 + r;
                C[(size_t)row * DIM + col] = acc[mi][ni][rr] + bv[ni];
            }
}

// -------- attn v2: one block per (b,h,f); stage once, compute both halves --
// 384 blocks x 448 thr. K/VT staged ONCE per frame (was twice). Packed-bf16
// shuffle transpose: 52 shuffles/thread (was 112), pre-scaled by inv at src.
__global__ __launch_bounds__(448)
void attn_kernel(__hip_bfloat16* qo,                        // [B*T,768] q in, o out
                 const __hip_bfloat16* __restrict__ kvb) {  // [B*T,1536] K|V
    __shared__ short sQ[210 * 66];     // 27,720 B (rows >=196 zero)
    __shared__ short sK[208 * 66];     // 27,456 B (rows >=196 zero)
    __shared__ short sVT[64 * 226];    // 28,928 B (cols j>=196 zero) tot 84,104
    int blk = blockIdx.x;
    int f = blk % NF, h = (blk / NF) % NH, b = blk / (NF * NH);
    size_t tok0 = (size_t)b * TT + (size_t)f * NP;
    int tid = threadIdx.x, wave = tid >> 6, lane = tid & 63;
    int r = lane & 15, q = lane >> 4;

    // ---- stage Q (210x8 chunks), K (208x8), VT (224 j x 64 d) — once
    for (int e = tid; e < 1680; e += 448) {
        int row = e >> 3, cg = e & 7;
        short8 t = {0,0,0,0,0,0,0,0};
        if (row < NP)
            __builtin_memcpy(&t, qo + (tok0 + row) * DIM + h * 64 + cg * 8, 16);
        __builtin_memcpy(&sQ[row * 66 + cg * 8], &t, 16);
    }
    for (int e = tid; e < 1664; e += 448) {
        int row = e >> 3, cg = e & 7;
        short8 t = {0,0,0,0,0,0,0,0};
        if (row < NP)
            __builtin_memcpy(&t, kvb + (tok0 + row) * 1536 + h * 64 + cg * 8, 16);
        __builtin_memcpy(&sK[row * 66 + cg * 8], &t, 16);
    }
    for (int jj = 0; jj < 224; jj += 28) {
        int j = jj + (tid >> 4);
        int d = (tid & 15) * 4;
        s16x4 v = {0, 0, 0, 0};
        if (j < NP)
            __builtin_memcpy(&v, kvb + (tok0 + j) * 1536 + DIM + h * 64 + d, 8);
#pragma unroll
        for (int i = 0; i < 4; i++) sVT[(d + i) * 226 + j] = v[i];
    }
    __syncthreads();   // the ONLY barrier

    for (int half = 0; half < 2; half++) {
        int row0 = half * 98;

        // ---- S^T = K @ Q^T for this wave's 16 Q-rows. C[m=j][n=i].
        f32x4 sacc[13];
        short8 qf0, qf1;
        __builtin_memcpy(&qf0, &sQ[(row0 + wave * 16 + r) * 66 + q * 8], 16);
        __builtin_memcpy(&qf1, &sQ[(row0 + wave * 16 + r) * 66 + 32 + q * 8], 16);
#pragma unroll
        for (int jf = 0; jf < 13; jf++) {
            f32x4 a = {};
            short8 kf;
            __builtin_memcpy(&kf, &sK[(jf * 16 + r) * 66 + q * 8], 16);
            a = __builtin_amdgcn_mfma_f32_16x16x32_bf16(kf, qf0, a, 0, 0, 0);
            __builtin_memcpy(&kf, &sK[(jf * 16 + r) * 66 + 32 + q * 8], 16);
            a = __builtin_amdgcn_mfma_f32_16x16x32_bf16(kf, qf1, a, 0, 0, 0);
            sacc[jf] = a;
        }

        // ---- softmax over j, in-lane (col i = r; j = jf*16 + q*4 + rg).
        const float scale = 0.125f;
        float mx = -INFINITY;
#pragma unroll
        for (int jf = 0; jf < 13; jf++)
#pragma unroll
            for (int rg = 0; rg < 4; rg++) {
                bool valid = (jf < 12) | (q == 0);
                if (valid) mx = fmaxf(mx, sacc[jf][rg] * scale);
            }
        mx = fmaxf(mx, __shfl_xor(mx, 16));
        mx = fmaxf(mx, __shfl_xor(mx, 32));
        float ps = 0.f;
#pragma unroll
        for (int jf = 0; jf < 13; jf++)
#pragma unroll
            for (int rg = 0; rg < 4; rg++) {
                bool valid = (jf < 12) | (q == 0);
                float p = valid ? __expf(sacc[jf][rg] * scale - mx) : 0.f;
                sacc[jf][rg] = p;
                ps += p;
            }
        ps += __shfl_xor(ps, 16);
        ps += __shfl_xor(ps, 32);
        float inv = 1.f / ps;

        // ---- packed shuffle transpose: pre-scale+pack bf16 pairs at source,
        // route 32-bit words. dest (r,q) elem e: frag 2c+(q>=2), reg e&3,
        // src lane ((2q + (e>>2)) & 3)*16 + r.
        uint pk01[13], pk23[13];
#pragma unroll
        for (int jf = 0; jf < 13; jf++) {
            pk01[jf] = pack2bf(sacc[jf][0] * inv, sacc[jf][1] * inv);
            pk23[jf] = pack2bf(sacc[jf][2] * inv, sacc[jf][3] * inv);
        }
        int sl = (((2 * q) & 3) << 4) | r;
        int sh = (((2 * q + 1) & 3) << 4) | r;
        bool hiq = q >= 2;
        short8 pa[7];
#pragma unroll
        for (int c = 0; c < 7; c++) {
            uint a0 = (uint)__shfl((int)pk01[2 * c], sl, 64);
            uint a1 = (uint)__shfl((int)pk23[2 * c], sl, 64);
            uint a2 = (uint)__shfl((int)pk01[2 * c], sh, 64);
            uint a3 = (uint)__shfl((int)pk23[2 * c], sh, 64);
            uint b0 = 0, b1 = 0, b2 = 0, b3 = 0;
            if (c < 6) {
                b0 = (uint)__shfl((int)pk01[2 * c + 1], sl, 64);
                b1 = (uint)__shfl((int)pk23[2 * c + 1], sl, 64);
                b2 = (uint)__shfl((int)pk01[2 * c + 1], sh, 64);
                b3 = (uint)__shfl((int)pk23[2 * c + 1], sh, 64);
            }
            uint w[4] = { hiq ? b0 : a0, hiq ? b1 : a1, hiq ? b2 : a2, hiq ? b3 : a3 };
            __builtin_memcpy(&pa[c], w, 16);
        }

        // ---- O = P @ VT. C[m=i][n=d]: 4 n-tiles x 7 k-chunks.
#pragma unroll
        for (int nt = 0; nt < 4; nt++) {
            f32x4 oacc = {};
#pragma unroll
            for (int kc = 0; kc < 7; kc++) {
                short8 bfv;
                __builtin_memcpy(&bfv, &sVT[(nt * 16 + r) * 226 + kc * 32 + q * 8], 16);
                oacc = __builtin_amdgcn_mfma_f32_16x16x32_bf16(pa[kc], bfv, oacc, 0, 0, 0);
            }
#pragma unroll
            for (int rg = 0; rg < 4; rg++) {
                int local = wave * 16 + q * 4 + rg;
                if (local < 98)
                    qo[(tok0 + row0 + local) * DIM + h * 64 + nt * 16 + r] =
                        __float2bfloat16(oacc[rg]);
            }
        }
    }
}

extern "C" void kernel_launch(void* const* d_in, const int* in_sizes, int n_in,
                              void* d_out, int out_size, void* d_ws, size_t ws_size,
                              hipStream_t stream) {
    const float* x     = (const float*)d_in[0];
    const float* ctx   = (const float*)d_in[1];
    const float* Wq    = (const float*)d_in[2];
    const float* Wkv   = (const float*)d_in[3];
    const float* Wo    = (const float*)d_in[4];
    const float* bo    = (const float*)d_in[5];
    const float* gamma = (const float*)d_in[6];
    const float* beta  = (const float*)d_in[7];
    // d_in[8] = mask: block-diagonal by frame, recomputed structurally.

    char* ws = (char*)d_ws;
    __hip_bfloat16* cbuf  = (__hip_bfloat16*)(ws + 0);           //  9,633,792
    __hip_bfloat16* kvbuf = (__hip_bfloat16*)(ws + 9633792);     // 19,267,584
    __hip_bfloat16* qbuf  = (__hip_bfloat16*)(ws + 28901376);    //  9,633,792
    __hip_bfloat16* WqT   = (__hip_bfloat16*)(ws + 38535168);    //  1,179,648
    __hip_bfloat16* WkvT  = (__hip_bfloat16*)(ws + 39714816);    //  2,359,296
    __hip_bfloat16* WoT   = (__hip_bfloat16*)(ws + 42074112);    //  1,179,648
    __hip_bfloat16* xnbuf = (__hip_bfloat16*)d_out;              //  dead until gemm_o
    float*          out   = (float*)d_out;

    prep_all<<<8576, 256, 0, stream>>>(Wq, Wkv, Wo, WqT, WkvT, WoT,
                                       ctx, cbuf, x, gamma, beta, xnbuf);
    gemm_qkv<<<225, 512, 0, stream>>>(xnbuf, cbuf, WqT, WkvT, qbuf, kvbuf);
    attn_kernel<<<NB * NH * NF, 448, 0, stream>>>(qbuf, kvbuf);
    gemm_o<<<294, 256, 0, stream>>>(qbuf, WoT, bo, out);
}

// Round 4
// 197.471 us; speedup vs baseline: 1.0784x; 1.0784x over previous
//
#include <hip/hip_runtime.h>
#include <hip/hip_bf16.h>

#define NB 2
#define TT 3136
#define DIM 768
#define NH 12
#define NF 16
#define NP 196

typedef __attribute__((ext_vector_type(8))) short short8;
typedef __attribute__((ext_vector_type(4))) short s16x4;
typedef __attribute__((ext_vector_type(4))) float f32x4;
typedef unsigned int uint;

__device__ __forceinline__ float bf2f(short s) {
    return __uint_as_float(((uint)(unsigned short)s) << 16);
}
__device__ __forceinline__ short f2bs(float f) {
    __hip_bfloat16 h = __float2bfloat16(f);
    short s; __builtin_memcpy(&s, &h, 2); return s;
}
__device__ __forceinline__ uint pack2bf(float a, float b) {
    return (uint)(unsigned short)f2bs(a) | ((uint)(unsigned short)f2bs(b) << 16);
}
__device__ __forceinline__ void load16_lds(const void* g, void* l) {
    __builtin_amdgcn_global_load_lds(
        (const __attribute__((address_space(1))) unsigned int*)g,
        (__attribute__((address_space(3))) unsigned int*)l, 16, 0, 0);
}

// -------- prep_all: Wq|Wkv|Wo transpose+bf16, ctx->bf16, LayerNorm(x) ------
__global__ __launch_bounds__(256)
void prep_all(const float* __restrict__ Wq, const float* __restrict__ Wkv,
              const float* __restrict__ Wo,
              __hip_bfloat16* __restrict__ WqT, __hip_bfloat16* __restrict__ WkvT,
              __hip_bfloat16* __restrict__ WoT,
              const float* __restrict__ ctx, __hip_bfloat16* __restrict__ cb,
              const float* __restrict__ x, const float* __restrict__ gamma,
              const float* __restrict__ beta, __hip_bfloat16* __restrict__ xn) {
    __shared__ float tile[32][33];
    int blk = blockIdx.x, tid = threadIdx.x;
    if (blk < 2304) {
        int bx = blk % 96, ky = blk / 96;
        const float* W; __hip_bfloat16* WT; int N, n0;
        if (bx < 24)      { W = Wq;  WT = WqT;  N = DIM;     n0 = bx * 32; }
        else if (bx < 72) { W = Wkv; WT = WkvT; N = 2 * DIM; n0 = (bx - 24) * 32; }
        else              { W = Wo;  WT = WoT;  N = DIM;     n0 = (bx - 72) * 32; }
        int k0 = ky * 32;
        int tx = tid & 31, ty = tid >> 5;
#pragma unroll
        for (int i = 0; i < 32; i += 8)
            tile[ty + i][tx] = W[(size_t)(k0 + ty + i) * N + (n0 + tx)];
        __syncthreads();
#pragma unroll
        for (int i = 0; i < 32; i += 8)
            WT[(size_t)(n0 + ty + i) * DIM + (k0 + tx)] = __float2bfloat16(tile[tx][ty + i]);
        return;
    }
    blk -= 2304;
    if (blk < 4704) {
        size_t i = (size_t)blk * 256 + tid;
        f32x4 f; __builtin_memcpy(&f, ctx + i * 4, 16);
        s16x4 s;
#pragma unroll
        for (int j = 0; j < 4; j++) s[j] = f2bs(f[j]);
        __builtin_memcpy((short*)cb + i * 4, &s, 8);
        return;
    }
    blk -= 4704;
    // LN: one row per wave, f32x4 loads, 64-lane butterfly (no barriers)
    int wave = tid >> 6, lane = tid & 63;
    int row = blk * 4 + wave;
    const float* xr = x + (size_t)row * DIM;
    f32x4 v[3];
    float s = 0.f, ss = 0.f;
#pragma unroll
    for (int i = 0; i < 3; i++) {
        __builtin_memcpy(&v[i], xr + lane * 4 + i * 256, 16);
#pragma unroll
        for (int j = 0; j < 4; j++) { s += v[i][j]; ss += v[i][j] * v[i][j]; }
    }
#pragma unroll
    for (int off = 32; off; off >>= 1) {
        s += __shfl_xor(s, off);
        ss += __shfl_xor(ss, off);
    }
    float mu = s / DIM;
    float rs = rsqrtf(ss / DIM - mu * mu + 1e-5f);
#pragma unroll
    for (int i = 0; i < 3; i++) {
        int c = lane * 4 + i * 256;
        f32x4 g, bt;
        __builtin_memcpy(&g, gamma + c, 16);
        __builtin_memcpy(&bt, beta + c, 16);
        s16x4 o;
#pragma unroll
        for (int j = 0; j < 4; j++) o[j] = f2bs((v[i][j] - mu) * rs * g[j] + bt[j]);
        __builtin_memcpy((short*)xn + (size_t)row * DIM + c, &o, 8);
    }
}

// -------- gemm_qkv: 256x256xBK64 phase-split template (unchanged r2) ------
__global__ __launch_bounds__(512, 1)
void gemm_qkv(const __hip_bfloat16* __restrict__ xn,
              const __hip_bfloat16* __restrict__ cb,
              const __hip_bfloat16* __restrict__ WqT,
              const __hip_bfloat16* __restrict__ WkvT,
              __hip_bfloat16* __restrict__ qbuf,
              __hip_bfloat16* __restrict__ kvbuf) {
    __shared__ short lds[2][2][2][8192];   // [buf][A/B][half][128*64] = 128 KB

    int orig = blockIdx.x;
    int xcd = orig & 7, pos = orig >> 3;
    int wgid = (xcd < 1 ? xcd * 29 : 29 + (xcd - 1) * 28) + pos;
    int mt = wgid / 9, nt = wgid - mt * 9;

    const __hip_bfloat16 *Abase, *Bbase; __hip_bfloat16* Cbase;
    int N, n0;
    if (nt < 3) { Abase = xn; Bbase = WqT;  Cbase = qbuf;  N = DIM;  n0 = nt * 256; }
    else        { Abase = cb; Bbase = WkvT; Cbase = kvbuf; N = 1536; n0 = (nt - 3) * 256; }
    int m0 = mt * 256;

    int tid = threadIdx.x, lane = tid & 63, wave = tid >> 6;
    int r = lane & 15, q = lane >> 4;
    int wm = wave >> 2, wn = wave & 3;
    f32x4 acc[8][4] = {};

    auto stageK = [&](int buf, int kt) {
        int k0 = kt * 64;
#pragma unroll
        for (int h = 0; h < 2; h++)
#pragma unroll
            for (int s = 0; s < 2; s++) {
                int idx = s * 512 + tid;
                int row = idx >> 3, cg = idx & 7;
                int w = (cg << 4) ^ ((row & 7) << 4);
                int grow = m0 + h * 128 + row;
                if (grow > TT * NB - 1) grow = TT * NB - 1;
                load16_lds((const char*)Abase + ((size_t)grow * DIM + k0) * 2 + w,
                           (char*)&lds[buf][0][h][0] + idx * 16);
            }
#pragma unroll
        for (int h = 0; h < 2; h++)
#pragma unroll
            for (int s = 0; s < 2; s++) {
                int idx = s * 512 + tid;
                int row = idx >> 3, cg = idx & 7;
                int w = (cg << 4) ^ ((row & 7) << 4);
                int grow = n0 + h * 128 + row;
                load16_lds((const char*)Bbase + ((size_t)grow * DIM + k0) * 2 + w,
                           (char*)&lds[buf][1][h][0] + idx * 16);
            }
    };

    auto read_frag = [&](const char* base, int frag, int ks) {
        short8 v;
        int row_ = frag * 16 + r;
        int byte_ = row_ * 128 + ((ks * 64 + q * 16) ^ ((r & 7) << 4));
        __builtin_memcpy(&v, base + byte_, 16);
        return v;
    };

    stageK(0, 0);
    asm volatile("s_waitcnt vmcnt(0)" ::: "memory");
    __builtin_amdgcn_s_barrier();

    for (int t = 0; t < 12; ++t) {
        int cur = t & 1;
        const char* Ah = (const char*)&lds[cur][0][wm][0];
        const char* Bh = (const char*)&lds[cur][1][wn >> 1][0];
        int bbase = (wn & 1) * 4;
        short8 breg[4][2];
#pragma unroll
        for (int p = 0; p < 4; p++) {
            short8 areg[2][2];
#pragma unroll
            for (int i = 0; i < 2; i++)
#pragma unroll
                for (int ks = 0; ks < 2; ks++)
                    areg[i][ks] = read_frag(Ah, p * 2 + i, ks);
            if (p == 0) {
#pragma unroll
                for (int n = 0; n < 4; n++)
#pragma unroll
                    for (int ks = 0; ks < 2; ks++)
                        breg[n][ks] = read_frag(Bh, bbase + n, ks);
                if (t < 11) stageK(cur ^ 1, t + 1);
            }
            __builtin_amdgcn_s_barrier();
            __builtin_amdgcn_s_setprio(1);
#pragma unroll
            for (int i = 0; i < 2; i++)
#pragma unroll
                for (int n = 0; n < 4; n++)
#pragma unroll
                    for (int ks = 0; ks < 2; ks++)
                        acc[p * 2 + i][n] = __builtin_amdgcn_mfma_f32_16x16x32_bf16(
                            areg[i][ks], breg[n][ks], acc[p * 2 + i][n], 0, 0, 0);
            __builtin_amdgcn_s_setprio(0);
            if (p == 3)
                asm volatile("s_waitcnt vmcnt(0)" ::: "memory");
            __builtin_amdgcn_s_barrier();
        }
    }

#pragma unroll
    for (int mf = 0; mf < 8; mf++)
#pragma unroll
        for (int n = 0; n < 4; n++)
#pragma unroll
            for (int rr = 0; rr < 4; rr++) {
                int row = m0 + wm * 128 + mf * 16 + q * 4 + rr;
                if (row < TT * NB) {
                    int col = n0 + wn * 64 + n * 16 + r;
                    Cbase[(size_t)row * N + col] = __float2bfloat16(acc[mf][n][rr]);
                }
            }
}

// -------- gemm_o: out(fp32) = qo @ WoT^T + bo (2-phase dbuf, unchanged) ----
__global__ __launch_bounds__(256)
void gemm_o(const __hip_bfloat16* __restrict__ A,
            const __hip_bfloat16* __restrict__ BT,
            const float* __restrict__ bias,
            float* __restrict__ C) {
    __shared__ short sA[2][128 * 64];
    __shared__ short sB[2][128 * 64];
    int orig = blockIdx.x;
    int xcd = orig & 7, pos = orig >> 3;
    int wgid = (xcd < 6 ? xcd * 37 : 222 + (xcd - 6) * 36) + pos;
    int mt = wgid / 6, nt = wgid - mt * 6;
    int m0 = mt * 128, n0 = nt * 128;
    int tid = threadIdx.x, lane = tid & 63, wave = tid >> 6;
    int r = lane & 15, q = lane >> 4;
    int wm = (wave & 1) * 64, wn = (wave >> 1) * 64;
    f32x4 acc[4][4] = {};

    auto stage = [&](int buf, int k0) {
#pragma unroll
        for (int i = 0; i < 4; i++) {
            int c = i * 256 + tid;
            int row = c >> 3, cg = c & 7;
            load16_lds(A + (size_t)(m0 + row) * DIM + k0 + cg * 8, &sA[buf][c * 8]);
        }
#pragma unroll
        for (int i = 0; i < 4; i++) {
            int c = i * 256 + tid;
            int row = c >> 3, cg = c & 7;
            load16_lds(BT + (size_t)(n0 + row) * DIM + k0 + cg * 8, &sB[buf][c * 8]);
        }
    };
    auto compute = [&](int buf) {
#pragma unroll
        for (int ks = 0; ks < 2; ks++) {
            short8 af[4], bfv[4];
#pragma unroll
            for (int t = 0; t < 4; t++) {
                __builtin_memcpy(&af[t],  &sA[buf][(wm + t * 16 + r) * 64 + ks * 32 + q * 8], 16);
                __builtin_memcpy(&bfv[t], &sB[buf][(wn + t * 16 + r) * 64 + ks * 32 + q * 8], 16);
            }
            __builtin_amdgcn_s_setprio(1);
#pragma unroll
            for (int mi = 0; mi < 4; mi++)
#pragma unroll
                for (int ni = 0; ni < 4; ni++)
                    acc[mi][ni] = __builtin_amdgcn_mfma_f32_16x16x32_bf16(
                        af[mi], bfv[ni], acc[mi][ni], 0, 0, 0);
            __builtin_amdgcn_s_setprio(0);
        }
    };

    stage(0, 0);
    __syncthreads();
    int cur = 0;
#pragma unroll 2
    for (int t = 0; t < 11; ++t) {
        stage(cur ^ 1, (t + 1) * 64);
        compute(cur);
        __syncthreads();
        cur ^= 1;
    }
    compute(cur);

    float bv[4];
#pragma unroll
    for (int ni = 0; ni < 4; ni++) bv[ni] = bias[n0 + wn + ni * 16 + r];
#pragma unroll
    for (int mi = 0; mi < 4; mi++)
#pragma unroll
        for (int ni = 0; ni < 4; ni++)
#pragma unroll
            for (int rr = 0; rr < 4; rr++) {
                int row = m0 + wm + mi * 16 + q * 4 + rr;
                int col = n0 + wn + ni * 16 + r;
                C[(size_t)row * DIM + col] = acc[mi][ni][rr] + bv[ni];
            }
}

// -------- attn v3: both halves per block, Q fragments direct to regs -------
// 384 blocks x 448 thr. LDS = K + VT only (56,384 B) -> 2 blocks/CU, 14
// waves/CU (v2's 84 KB broke residency: 2x84480 > 160 KB -> 7 waves, -11 us).
// Each wave loads its own 16 Q-rows' fragments global->reg (4x16B), latency
// hidden under K/V staging. Packed-bf16 shuffle transpose kept from v2.
__global__ __launch_bounds__(448, 4)
void attn_kernel(__hip_bfloat16* qo,                        // [B*T,768] q in, o out
                 const __hip_bfloat16* __restrict__ kvb) {  // [B*T,1536] K|V
    __shared__ short sK[208 * 66];     // 27,456 B (rows >=196 zero)
    __shared__ short sVT[64 * 226];    // 28,928 B (cols j>=196 zero) tot 56,384
    int blk = blockIdx.x;
    int f = blk % NF, h = (blk / NF) % NH, b = blk / (NF * NH);
    size_t tok0 = (size_t)b * TT + (size_t)f * NP;
    int tid = threadIdx.x, wave = tid >> 6, lane = tid & 63;
    int r = lane & 15, q = lane >> 4;

    // ---- Q fragments for both halves, direct global->reg (issue first so
    // the ~600cy latency hides under the K/V staging below).
    short8 qf[2][2];
#pragma unroll
    for (int half = 0; half < 2; half++) {
        int qrow = half * 98 + wave * 16 + r;
        if (qrow >= NP) qrow = 0;      // clamped lanes' outputs never stored
        const __hip_bfloat16* src = qo + (tok0 + qrow) * DIM + h * 64;
        __builtin_memcpy(&qf[half][0], src + q * 8, 16);
        __builtin_memcpy(&qf[half][1], src + 32 + q * 8, 16);
    }

    // ---- stage K (208x8 chunks), VT (224 j x 64 d) — once per frame
    for (int e = tid; e < 1664; e += 448) {
        int row = e >> 3, cg = e & 7;
        short8 t = {0,0,0,0,0,0,0,0};
        if (row < NP)
            __builtin_memcpy(&t, kvb + (tok0 + row) * 1536 + h * 64 + cg * 8, 16);
        __builtin_memcpy(&sK[row * 66 + cg * 8], &t, 16);
    }
    for (int jj = 0; jj < 224; jj += 28) {
        int j = jj + (tid >> 4);
        int d = (tid & 15) * 4;
        s16x4 v = {0, 0, 0, 0};
        if (j < NP)
            __builtin_memcpy(&v, kvb + (tok0 + j) * 1536 + DIM + h * 64 + d, 8);
#pragma unroll
        for (int i = 0; i < 4; i++) sVT[(d + i) * 226 + j] = v[i];
    }
    __syncthreads();   // the ONLY barrier

#pragma unroll
    for (int half = 0; half < 2; half++) {
        int row0 = half * 98;

        // ---- S^T = K @ Q^T for this wave's 16 Q-rows. C[m=j][n=i].
        f32x4 sacc[13];
#pragma unroll
        for (int jf = 0; jf < 13; jf++) {
            f32x4 a = {};
            short8 kf;
            __builtin_memcpy(&kf, &sK[(jf * 16 + r) * 66 + q * 8], 16);
            a = __builtin_amdgcn_mfma_f32_16x16x32_bf16(kf, qf[half][0], a, 0, 0, 0);
            __builtin_memcpy(&kf, &sK[(jf * 16 + r) * 66 + 32 + q * 8], 16);
            a = __builtin_amdgcn_mfma_f32_16x16x32_bf16(kf, qf[half][1], a, 0, 0, 0);
            sacc[jf] = a;
        }

        // ---- softmax over j, in-lane (col i = r; j = jf*16 + q*4 + rg).
        const float scale = 0.125f;
        float mx = -INFINITY;
#pragma unroll
        for (int jf = 0; jf < 13; jf++)
#pragma unroll
            for (int rg = 0; rg < 4; rg++) {
                bool valid = (jf < 12) | (q == 0);
                if (valid) mx = fmaxf(mx, sacc[jf][rg] * scale);
            }
        mx = fmaxf(mx, __shfl_xor(mx, 16));
        mx = fmaxf(mx, __shfl_xor(mx, 32));
        float ps = 0.f;
#pragma unroll
        for (int jf = 0; jf < 13; jf++)
#pragma unroll
            for (int rg = 0; rg < 4; rg++) {
                bool valid = (jf < 12) | (q == 0);
                float p = valid ? __expf(sacc[jf][rg] * scale - mx) : 0.f;
                sacc[jf][rg] = p;
                ps += p;
            }
        ps += __shfl_xor(ps, 16);
        ps += __shfl_xor(ps, 32);
        float inv = 1.f / ps;

        // ---- packed shuffle transpose (52 shuffles): pre-scale+pack bf16
        // pairs at source, route 32-bit words.
        uint pk01[13], pk23[13];
#pragma unroll
        for (int jf = 0; jf < 13; jf++) {
            pk01[jf] = pack2bf(sacc[jf][0] * inv, sacc[jf][1] * inv);
            pk23[jf] = pack2bf(sacc[jf][2] * inv, sacc[jf][3] * inv);
        }
        int sl = (((2 * q) & 3) << 4) | r;
        int sh = (((2 * q + 1) & 3) << 4) | r;
        bool hiq = q >= 2;
        short8 pa[7];
#pragma unroll
        for (int c = 0; c < 7; c++) {
            uint a0 = (uint)__shfl((int)pk01[2 * c], sl, 64);
            uint a1 = (uint)__shfl((int)pk23[2 * c], sl, 64);
            uint a2 = (uint)__shfl((int)pk01[2 * c], sh, 64);
            uint a3 = (uint)__shfl((int)pk23[2 * c], sh, 64);
            uint b0 = 0, b1 = 0, b2 = 0, b3 = 0;
            if (c < 6) {
                b0 = (uint)__shfl((int)pk01[2 * c + 1], sl, 64);
                b1 = (uint)__shfl((int)pk23[2 * c + 1], sl, 64);
                b2 = (uint)__shfl((int)pk01[2 * c + 1], sh, 64);
                b3 = (uint)__shfl((int)pk23[2 * c + 1], sh, 64);
            }
            uint w[4] = { hiq ? b0 : a0, hiq ? b1 : a1, hiq ? b2 : a2, hiq ? b3 : a3 };
            __builtin_memcpy(&pa[c], w, 16);
        }

        // ---- O = P @ VT. C[m=i][n=d]: 4 n-tiles x 7 k-chunks.
#pragma unroll
        for (int nt = 0; nt < 4; nt++) {
            f32x4 oacc = {};
#pragma unroll
            for (int kc = 0; kc < 7; kc++) {
                short8 bfv;
                __builtin_memcpy(&bfv, &sVT[(nt * 16 + r) * 226 + kc * 32 + q * 8], 16);
                oacc = __builtin_amdgcn_mfma_f32_16x16x32_bf16(pa[kc], bfv, oacc, 0, 0, 0);
            }
#pragma unroll
            for (int rg = 0; rg < 4; rg++) {
                int local = wave * 16 + q * 4 + rg;
                if (local < 98)
                    qo[(tok0 + row0 + local) * DIM + h * 64 + nt * 16 + r] =
                        __float2bfloat16(oacc[rg]);
            }
        }
    }
}

extern "C" void kernel_launch(void* const* d_in, const int* in_sizes, int n_in,
                              void* d_out, int out_size, void* d_ws, size_t ws_size,
                              hipStream_t stream) {
    const float* x     = (const float*)d_in[0];
    const float* ctx   = (const float*)d_in[1];
    const float* Wq    = (const float*)d_in[2];
    const float* Wkv   = (const float*)d_in[3];
    const float* Wo    = (const float*)d_in[4];
    const float* bo    = (const float*)d_in[5];
    const float* gamma = (const float*)d_in[6];
    const float* beta  = (const float*)d_in[7];
    // d_in[8] = mask: block-diagonal by frame, recomputed structurally.

    char* ws = (char*)d_ws;
    __hip_bfloat16* cbuf  = (__hip_bfloat16*)(ws + 0);           //  9,633,792
    __hip_bfloat16* kvbuf = (__hip_bfloat16*)(ws + 9633792);     // 19,267,584
    __hip_bfloat16* qbuf  = (__hip_bfloat16*)(ws + 28901376);    //  9,633,792
    __hip_bfloat16* WqT   = (__hip_bfloat16*)(ws + 38535168);    //  1,179,648
    __hip_bfloat16* WkvT  = (__hip_bfloat16*)(ws + 39714816);    //  2,359,296
    __hip_bfloat16* WoT   = (__hip_bfloat16*)(ws + 42074112);    //  1,179,648
    __hip_bfloat16* xnbuf = (__hip_bfloat16*)d_out;              //  dead until gemm_o
    float*          out   = (float*)d_out;

    prep_all<<<8576, 256, 0, stream>>>(Wq, Wkv, Wo, WqT, WkvT, WoT,
                                       ctx, cbuf, x, gamma, beta, xnbuf);
    gemm_qkv<<<225, 512, 0, stream>>>(xnbuf, cbuf, WqT, WkvT, qbuf, kvbuf);
    attn_kernel<<<NB * NH * NF, 448, 0, stream>>>(qbuf, kvbuf);
    gemm_o<<<294, 256, 0, stream>>>(qbuf, WoT, bo, out);
}